// Round 3
// baseline (1366.664 us; speedup 1.0000x reference)
//
#include <hip/hip_runtime.h>
#include <hip/hip_bf16.h>
#include <stdint.h>

#define BB 8
#define CC 512
#define NN 4096
#define QB 64
#define KB 64
#define D4 2048
#define NT (NN / KB)

typedef short bf8 __attribute__((ext_vector_type(8)));
typedef float f32x4 __attribute__((ext_vector_type(4)));

__device__ __forceinline__ uint16_t f2bf(float f) {
  uint32_t u = __builtin_bit_cast(uint32_t, f);
  u = (u + 0x7FFFu + ((u >> 16) & 1u)) >> 16;
  return (uint16_t)u;
}

// [B,C,N] fp32 -> [B,N,C] bf16 (with optional scalar scale folded in)
__global__ __launch_bounds__(256) void transpose_cast_k(const float* __restrict__ src,
                                                        uint16_t* __restrict__ dst,
                                                        float scale) {
  __shared__ float tile[32][33];
  int b = blockIdx.z;
  int n0 = blockIdx.x * 32, c0 = blockIdx.y * 32;
  int tx = threadIdx.x & 31, ty = threadIdx.x >> 5;
  const float* s = src + ((size_t)b * CC + c0) * NN + n0;
#pragma unroll
  for (int i = 0; i < 4; i++) {
    int c = ty + i * 8;
    tile[tx][c] = s[(size_t)c * NN + tx];
  }
  __syncthreads();
  uint16_t* d = dst + ((size_t)b * NN + n0) * CC + c0;
#pragma unroll
  for (int i = 0; i < 4; i++) {
    int n = ty + i * 8;
    d[(size_t)n * CC + tx] = f2bf(tile[n][tx] * scale);
  }
}

__global__ __launch_bounds__(256) void cast_k(const float* __restrict__ in,
                                              uint16_t* __restrict__ out, int n) {
  int i = (blockIdx.x * 256 + threadIdx.x) * 4;
  if (i >= n) return;
  float4 v = *(const float4*)(in + i);
  ushort4 o;
  o.x = f2bf(v.x); o.y = f2bf(v.y); o.z = f2bf(v.z); o.w = f2bf(v.w);
  *(ushort4*)(out + i) = o;
}

// Fused flash-attention + FFN. Grid: (NN/QB, BB), 512 threads (8 waves).
__global__ __launch_bounds__(512, 2) void attn_ffn_k(
    const uint16_t* __restrict__ Qt, const uint16_t* __restrict__ Kt,
    const uint16_t* __restrict__ Vc, const uint16_t* __restrict__ W1b,
    const uint16_t* __restrict__ W2b, const float* __restrict__ b1,
    const float* __restrict__ b2, const float* __restrict__ gma,
    const float* __restrict__ qry, float* __restrict__ out) {
  __shared__ __attribute__((aligned(16))) uint16_t Os[QB][CC];  // 64 KB: FFN O-tile (scratch in loop)
  __shared__ __attribute__((aligned(16))) uint16_t Ks[KB][CC];  // 64 KB swizzled
  __shared__ __attribute__((aligned(16))) float Ss[QB][68];     // 17408 B
  __shared__ __attribute__((aligned(16))) uint16_t Ps[QB][KB];  // 8 KB swizzled
  __shared__ float mst[QB];
  __shared__ float lst[QB];
  __shared__ float rsc[QB];  // total 157440 B

  const int bid = blockIdx.x + gridDim.x * blockIdx.y;
  const int b = bid & 7;          // batch == XCD round-robin
  const int n0 = (bid >> 3) * QB;
  const int tid = threadIdx.x;
  const int lane = tid & 63, wid = tid >> 6;
  const int lhi = lane >> 4, llo = lane & 15;
  const int r7 = llo & 7;         // == (fragment row)&7 for all 16-aligned row bases

  const int srt = wid >> 1;        // S row-tile (q), waves pair up
  const int sct0 = (wid & 1) * 2;  // S col-tiles (k): sct0, sct0+1

  // Q fragments -> registers (once; Q never touches LDS)
  bf8 qf[16];
  {
    const uint16_t* qsrc = Qt + ((size_t)b * NN + n0 + srt * 16 + llo) * CC + lhi * 8;
#pragma unroll
    for (int kc = 0; kc < 16; kc++) qf[kc] = *(const bf8*)(qsrc + kc * 32);
  }

  // K tile 0: global -> reg -> LDS (pre-swizzled source, linear LDS)
  uint4 kreg[8];
#pragma unroll
  for (int j = 0; j < 8; j++) {
    const int r = wid * 8 + j;
    kreg[j] = *(const uint4*)(Kt + ((size_t)b * NN + r) * CC + ((lane ^ (r & 7)) << 3));
  }
#pragma unroll
  for (int j = 0; j < 8; j++) {
    const int r = wid * 8 + j;
    *(uint4*)(&Ks[r][0] + lane * 8) = kreg[j];
  }
  if (tid < QB) { mst[tid] = -__builtin_inff(); lst[tid] = 0.f; }

  const f32x4 vzero = {0.f, 0.f, 0.f, 0.f};
  f32x4 acc[4][4];
#pragma unroll
  for (int i = 0; i < 4; i++)
#pragma unroll
    for (int j = 0; j < 4; j++) acc[i][j] = vzero;

  const uint16_t* k0row = &Ks[sct0 * 16 + llo][0];
  const uint16_t* k1row = &Ks[sct0 * 16 + 16 + llo][0];
  const uint16_t* vbase = Vc + ((size_t)b * CC + wid * 64 + llo) * NN + lhi * 8;

  for (int it = 0; it < NT; it++) {
    const int m0 = it * KB;
    __syncthreads();  // B1: K tile it ready in LDS

    // S = Q.K^T — Q from regs, K via swizzled conflict-free ds_read_b128
    f32x4 s0 = vzero, s1 = vzero;
    __builtin_amdgcn_s_setprio(1);
#pragma unroll
    for (int kc = 0; kc < 16; kc++) {
      const int g = ((kc * 4 + lhi) ^ r7) << 3;
      bf8 bk0 = *(const bf8*)(k0row + g);
      bf8 bk1 = *(const bf8*)(k1row + g);
      s0 = __builtin_amdgcn_mfma_f32_16x16x32_bf16(qf[kc], bk0, s0, 0, 0, 0);
      s1 = __builtin_amdgcn_mfma_f32_16x16x32_bf16(qf[kc], bk1, s1, 0, 0, 0);
    }
    __builtin_amdgcn_s_setprio(0);
    {
      const int n = srt * 16 + lhi * 4;
#pragma unroll
      for (int r = 0; r < 4; r++) {
        Ss[n + r][sct0 * 16 + llo] = s0[r];
        Ss[n + r][sct0 * 16 + 16 + llo] = s1[r];
      }
    }
    __syncthreads();  // B2: S visible, all Ks reads done

    // V fragments (oldest loads -> PV waits only these, K prefetch stays in flight)
    bf8 av[2][4];
#pragma unroll
    for (int ks = 0; ks < 2; ks++)
#pragma unroll
      for (int rt = 0; rt < 4; rt++)
        av[ks][rt] = *(const bf8*)(vbase + (size_t)rt * 16 * NN + m0 + ks * 32);

    // K tile it+1: global -> reg (latency hides under softmax + B3 + PV)
    if (it + 1 < NT) {
#pragma unroll
      for (int j = 0; j < 8; j++) {
        const int r = wid * 8 + j;
        kreg[j] = *(const uint4*)(Kt + ((size_t)b * NN + m0 + KB + r) * CC + ((lane ^ (r & 7)) << 3));
      }
    }

    // online softmax: 8 threads per row; P packed to one swizzled b128 write
    {
      const int row = tid >> 3, j = tid & 7;
      const int rw7 = row & 7;
      float sv[8];
      *(float4*)&sv[0] = *(const float4*)&Ss[row][j * 8];
      *(float4*)&sv[4] = *(const float4*)&Ss[row][j * 8 + 4];
      float mx = fmaxf(fmaxf(fmaxf(sv[0], sv[1]), fmaxf(sv[2], sv[3])),
                       fmaxf(fmaxf(sv[4], sv[5]), fmaxf(sv[6], sv[7])));
      mx = fmaxf(mx, __shfl_xor(mx, 1, 8));
      mx = fmaxf(mx, __shfl_xor(mx, 2, 8));
      mx = fmaxf(mx, __shfl_xor(mx, 4, 8));
      const float mo = mst[row];
      const float nm = fmaxf(mo, mx);
      const float rs = __expf(mo - nm);
      float p[8], psum = 0.f;
#pragma unroll
      for (int k2 = 0; k2 < 8; k2++) {
        p[k2] = __expf(sv[k2] - nm);
        psum += p[k2];
      }
      bf8 pk;
#pragma unroll
      for (int k2 = 0; k2 < 8; k2++) pk[k2] = (short)f2bf(p[k2]);
      *(bf8*)(&Ps[row][0] + ((j ^ rw7) << 3)) = pk;
      psum += __shfl_xor(psum, 1, 8);
      psum += __shfl_xor(psum, 2, 8);
      psum += __shfl_xor(psum, 4, 8);
      if (j == 0) { lst[row] = lst[row] * rs + psum; mst[row] = nm; rsc[row] = rs; }
    }
    __syncthreads();  // B3: P + rsc ready

    // rescale (cols = n) then PV: acc[c][n] += V[c][m]·P[n][m]
    float rsn[4];
#pragma unroll
    for (int nt = 0; nt < 4; nt++) rsn[nt] = rsc[nt * 16 + llo];
#pragma unroll
    for (int rt = 0; rt < 4; rt++)
#pragma unroll
      for (int nt = 0; nt < 4; nt++) acc[rt][nt] *= rsn[nt];

    __builtin_amdgcn_s_setprio(1);
#pragma unroll
    for (int ks = 0; ks < 2; ks++) {
      bf8 bp[4];
#pragma unroll
      for (int nt = 0; nt < 4; nt++)
        bp[nt] = *(const bf8*)(&Ps[nt * 16 + llo][0] + ((((ks << 2) + lhi) ^ r7) << 3));
#pragma unroll
      for (int rt = 0; rt < 4; rt++)
#pragma unroll
        for (int nt = 0; nt < 4; nt++)
          acc[rt][nt] = __builtin_amdgcn_mfma_f32_16x16x32_bf16(av[ks][rt], bp[nt], acc[rt][nt], 0, 0, 0);
    }
    __builtin_amdgcn_s_setprio(0);

    // write next K tile to LDS (reads of Ks ended at B2; B1 publishes)
    if (it + 1 < NT) {
#pragma unroll
      for (int j = 0; j < 8; j++) {
        const int r = wid * 8 + j;
        *(uint4*)(&Ks[r][0] + lane * 8) = kreg[j];
      }
    }
  }

  float invl[4];
#pragma unroll
  for (int nt = 0; nt < 4; nt++) invl[nt] = 1.0f / lst[nt * 16 + llo];

  // O[n][c] bf16 -> Os (swizzled granule layout)
  uint16_t(*Old)[CC] = Os;
#pragma unroll
  for (int rt = 0; rt < 4; rt++)
#pragma unroll
    for (int nt = 0; nt < 4; nt++) {
      ushort4 o4;
      o4.x = f2bf(acc[rt][nt][0] * invl[nt]);
      o4.y = f2bf(acc[rt][nt][1] * invl[nt]);
      o4.z = f2bf(acc[rt][nt][2] * invl[nt]);
      o4.w = f2bf(acc[rt][nt][3] * invl[nt]);
      const int gch = wid * 8 + rt * 2 + (lhi >> 1);
      *(ushort4*)(&Old[nt * 16 + llo][0] + ((gch ^ r7) << 3) + ((lhi & 1) << 2)) = o4;
    }

  // FFN: hidden in 4 d-quarters through Hs (overlay on Ks, swizzled)
  uint16_t(*Hs)[CC] = Ks;
  f32x4 facc[4][4];
#pragma unroll
  for (int i = 0; i < 4; i++)
#pragma unroll
    for (int j = 0; j < 4; j++) facc[i][j] = vzero;
  const float g = gma[0];
  const uint16_t* orow[4];
  const uint16_t* hrow[4];
#pragma unroll
  for (int nt = 0; nt < 4; nt++) {
    orow[nt] = &Old[nt * 16 + llo][0];
    hrow[nt] = &Hs[nt * 16 + llo][0];
  }

  for (int qtr = 0; qtr < 4; qtr++) {
    const int dq0 = qtr * 512;
    f32x4 hacc[4][4];
#pragma unroll
    for (int i = 0; i < 4; i++)
#pragma unroll
      for (int j = 0; j < 4; j++) hacc[i][j] = vzero;
    __syncthreads();  // prev quarter's Hs reads done; O-writes visible (qtr 0)
    __builtin_amdgcn_s_setprio(1);
#pragma unroll 2
    for (int kc8 = 0; kc8 < 64; kc8 += 4) {
      bf8 bo[4], aw[4];
      const int gof = ((kc8 + lhi) ^ r7) << 3;
#pragma unroll
      for (int nt = 0; nt < 4; nt++) bo[nt] = *(const bf8*)(orow[nt] + gof);
#pragma unroll
      for (int dt = 0; dt < 4; dt++) {
        const int d = dq0 + wid * 64 + dt * 16 + llo;
        aw[dt] = *(const bf8*)(W1b + (size_t)d * CC + (kc8 + lhi) * 8);
      }
#pragma unroll
      for (int dt = 0; dt < 4; dt++)
#pragma unroll
        for (int nt = 0; nt < 4; nt++)
          hacc[dt][nt] = __builtin_amdgcn_mfma_f32_16x16x32_bf16(aw[dt], bo[nt], hacc[dt][nt], 0, 0, 0);
    }
    __builtin_amdgcn_s_setprio(0);
#pragma unroll
    for (int dt = 0; dt < 4; dt++) {
      const int dg = dq0 + wid * 64 + dt * 16 + lhi * 4;
      const float4 b1v = *(const float4*)(b1 + dg);
#pragma unroll
      for (int nt = 0; nt < 4; nt++) {
        ushort4 h4;
        h4.x = f2bf(fmaxf(hacc[dt][nt][0] + b1v.x, 0.f));
        h4.y = f2bf(fmaxf(hacc[dt][nt][1] + b1v.y, 0.f));
        h4.z = f2bf(fmaxf(hacc[dt][nt][2] + b1v.z, 0.f));
        h4.w = f2bf(fmaxf(hacc[dt][nt][3] + b1v.w, 0.f));
        const int gch = wid * 8 + dt * 2 + (lhi >> 1);
        *(ushort4*)(&Hs[nt * 16 + llo][0] + ((gch ^ r7) << 3) + ((lhi & 1) << 2)) = h4;
      }
    }
    __syncthreads();  // hidden quarter ready
    __builtin_amdgcn_s_setprio(1);
#pragma unroll 2
    for (int kd8 = 0; kd8 < 64; kd8 += 4) {
      bf8 ah[4], bw[4];
      const int gof = ((kd8 + lhi) ^ r7) << 3;
#pragma unroll
      for (int nt = 0; nt < 4; nt++) ah[nt] = *(const bf8*)(hrow[nt] + gof);
#pragma unroll
      for (int ct = 0; ct < 4; ct++) {
        const int c = wid * 64 + ct * 16 + llo;
        bw[ct] = *(const bf8*)(W2b + (size_t)c * D4 + dq0 + (kd8 + lhi) * 8);
      }
#pragma unroll
      for (int nt = 0; nt < 4; nt++)
#pragma unroll
        for (int ct = 0; ct < 4; ct++)
          facc[nt][ct] = __builtin_amdgcn_mfma_f32_16x16x32_bf16(ah[nt], bw[ct], facc[nt][ct], 0, 0, 0);
    }
    __builtin_amdgcn_s_setprio(0);
  }

  // epilogue: out[b,c,n] = (facc + b2[c])*gamma + query  (float4 along n)
#pragma unroll
  for (int nt = 0; nt < 4; nt++) {
    const int n = n0 + nt * 16 + lhi * 4;
#pragma unroll
    for (int ct = 0; ct < 4; ct++) {
      const int c = wid * 64 + ct * 16 + llo;
      const float b2c = b2[c];
      const size_t off = ((size_t)b * CC + c) * NN + n;
      const float4 q4 = *(const float4*)(qry + off);
      float4 o4;
      o4.x = (facc[nt][ct][0] + b2c) * g + q4.x;
      o4.y = (facc[nt][ct][1] + b2c) * g + q4.y;
      o4.z = (facc[nt][ct][2] + b2c) * g + q4.z;
      o4.w = (facc[nt][ct][3] + b2c) * g + q4.w;
      *(float4*)(out + off) = o4;
    }
  }
}

extern "C" void kernel_launch(void* const* d_in, const int* in_sizes, int n_in,
                              void* d_out, int out_size, void* d_ws, size_t ws_size,
                              hipStream_t stream) {
  const float* q = (const float*)d_in[0];
  const float* k = (const float*)d_in[1];
  const float* v = (const float*)d_in[2];
  const float* w1 = (const float*)d_in[3];
  const float* b1 = (const float*)d_in[4];
  const float* w2 = (const float*)d_in[5];
  const float* b2 = (const float*)d_in[6];
  const float* gm = (const float*)d_in[7];
  float* out = (float*)d_out;

  uint16_t* Qt = (uint16_t*)d_ws;                    // [B][N][C] bf16 (pre-scaled)
  uint16_t* Kt = Qt + (size_t)BB * NN * CC;          // [B][N][C] bf16
  uint16_t* Vc = Kt + (size_t)BB * NN * CC;          // [B][C][N] bf16
  uint16_t* W1b = Vc + (size_t)BB * NN * CC;         // [2048][512] bf16
  uint16_t* W2b = W1b + (size_t)D4 * CC;             // [512][2048] bf16

  dim3 tgrid(NN / 32, CC / 32, BB);
  transpose_cast_k<<<tgrid, 256, 0, stream>>>(q, Qt, 0.044194173824159216f);
  transpose_cast_k<<<tgrid, 256, 0, stream>>>(k, Kt, 1.0f);
  cast_k<<<(BB * CC * NN / 4 + 255) / 256, 256, 0, stream>>>(v, Vc, BB * CC * NN);
  cast_k<<<(D4 * CC / 4 + 255) / 256, 256, 0, stream>>>(w1, W1b, D4 * CC);
  cast_k<<<(CC * D4 / 4 + 255) / 256, 256, 0, stream>>>(w2, W2b, CC * D4);
  attn_ffn_k<<<dim3(NN / QB, BB), 512, 0, stream>>>(Qt, Kt, Vc, W1b, W2b, b1, b2, gm, q, out);
}

// Round 4
// 868.073 us; speedup vs baseline: 1.5744x; 1.5744x over previous
//
#include <hip/hip_runtime.h>
#include <hip/hip_bf16.h>
#include <stdint.h>

#define BB 8
#define CC 512
#define NN 4096
#define QB 64
#define KB 64
#define D4 2048
#define NT (NN / KB)

typedef short bf8 __attribute__((ext_vector_type(8)));
typedef float f32x4 __attribute__((ext_vector_type(4)));

__device__ __forceinline__ uint16_t f2bf(float f) {
  uint32_t u = __builtin_bit_cast(uint32_t, f);
  u = (u + 0x7FFFu + ((u >> 16) & 1u)) >> 16;
  return (uint16_t)u;
}

__device__ __forceinline__ void gl_lds16(const void* g, void* l) {
  __builtin_amdgcn_global_load_lds((__attribute__((address_space(1))) void*)g,
                                   (__attribute__((address_space(3))) void*)l, 16, 0, 0);
}

// stage 64 rows x 512 u16 tile: global (row stride CC) -> LDS [64][512] linear,
// per-row XOR swizzle applied to the GLOBAL source (granule l holds chunk l^(r&7)).
__device__ __forceinline__ void stage_tile(const uint16_t* __restrict__ src,
                                           uint16_t* dst, int wid, int lane) {
#pragma unroll
  for (int j = 0; j < 8; j++) {
    const int r = wid * 8 + j;
    gl_lds16(src + (size_t)r * CC + ((lane ^ (r & 7)) << 3), dst + r * CC);
  }
}

// [B,C,N] fp32 -> [B,N,C] bf16 (with optional scalar scale folded in)
__global__ __launch_bounds__(256) void transpose_cast_k(const float* __restrict__ src,
                                                        uint16_t* __restrict__ dst,
                                                        float scale) {
  __shared__ float tile[32][33];
  int b = blockIdx.z;
  int n0 = blockIdx.x * 32, c0 = blockIdx.y * 32;
  int tx = threadIdx.x & 31, ty = threadIdx.x >> 5;
  const float* s = src + ((size_t)b * CC + c0) * NN + n0;
#pragma unroll
  for (int i = 0; i < 4; i++) {
    int c = ty + i * 8;
    tile[tx][c] = s[(size_t)c * NN + tx];
  }
  __syncthreads();
  uint16_t* d = dst + ((size_t)b * NN + n0) * CC + c0;
#pragma unroll
  for (int i = 0; i < 4; i++) {
    int n = ty + i * 8;
    d[(size_t)n * CC + tx] = f2bf(tile[n][tx] * scale);
  }
}

__global__ __launch_bounds__(256) void cast_k(const float* __restrict__ in,
                                              uint16_t* __restrict__ out, int n) {
  int i = (blockIdx.x * 256 + threadIdx.x) * 4;
  if (i >= n) return;
  float4 v = *(const float4*)(in + i);
  ushort4 o;
  o.x = f2bf(v.x); o.y = f2bf(v.y); o.z = f2bf(v.z); o.w = f2bf(v.w);
  *(ushort4*)(out + i) = o;
}

// Fused flash-attention + FFN. Grid: (NN/QB, BB), 512 threads (8 waves).
// LDS limits to 1 block/CU (8 waves = 2 waves/EU) -> pin that so the register
// allocator gets the full 256-VGPR budget (R3's spill came from a 128 cap).
__global__ __launch_bounds__(512) __attribute__((amdgpu_waves_per_eu(2, 2))) void attn_ffn_k(
    const uint16_t* __restrict__ Qt, const uint16_t* __restrict__ Kt,
    const uint16_t* __restrict__ Vc, const uint16_t* __restrict__ W1b,
    const uint16_t* __restrict__ W2b, const float* __restrict__ b1,
    const float* __restrict__ b2, const float* __restrict__ gma,
    const float* __restrict__ qry, float* __restrict__ out) {
  __shared__ __attribute__((aligned(16))) uint16_t Os[QB][CC];  // 64 KB: FFN O-tile
  __shared__ __attribute__((aligned(16))) uint16_t Ks[KB][CC];  // 64 KB swizzled
  __shared__ __attribute__((aligned(16))) float Ss[QB][68];     // 17408 B
  __shared__ __attribute__((aligned(16))) uint16_t Ps[QB][KB];  // 8 KB swizzled
  __shared__ float mst[QB];
  __shared__ float lst[QB];
  __shared__ float rsc[QB];  // total 157440 B

  const int bid = blockIdx.x + gridDim.x * blockIdx.y;
  const int b = bid & 7;          // batch == XCD round-robin
  const int n0 = (bid >> 3) * QB;
  const int tid = threadIdx.x;
  const int lane = tid & 63, wid = tid >> 6;
  const int lhi = lane >> 4, llo = lane & 15;
  const int r7 = llo & 7;

  const int srt = wid >> 1;        // S row-tile (q), waves pair up
  const int sct0 = (wid & 1) * 2;  // S col-tiles (k): sct0, sct0+1

  // Q fragments -> registers (once; Q never touches LDS)
  bf8 qf[16];
  {
    const uint16_t* qsrc = Qt + ((size_t)b * NN + n0 + srt * 16 + llo) * CC + lhi * 8;
#pragma unroll
    for (int kc = 0; kc < 16; kc++) qf[kc] = *(const bf8*)(qsrc + kc * 32);
  }

  // K tile 0: DMA global -> LDS (pre-swizzled source, linear dest)
  stage_tile(Kt + (size_t)b * NN * CC, &Ks[0][0], wid, lane);
  if (tid < QB) { mst[tid] = -__builtin_inff(); lst[tid] = 0.f; }

  const f32x4 vzero = {0.f, 0.f, 0.f, 0.f};
  f32x4 acc[4][4];
#pragma unroll
  for (int i = 0; i < 4; i++)
#pragma unroll
    for (int j = 0; j < 4; j++) acc[i][j] = vzero;

  const uint16_t* k0row = &Ks[sct0 * 16 + llo][0];
  const uint16_t* k1row = &Ks[sct0 * 16 + 16 + llo][0];
  const uint16_t* vbase = Vc + ((size_t)b * CC + wid * 64 + llo) * NN + lhi * 8;

  for (int it = 0; it < NT; it++) {
    const int m0 = it * KB;
    __syncthreads();  // B1: K tile it ready (drains DMA vmcnt)

    // S = Q.K^T — Q from regs, K via swizzled conflict-free ds_read_b128
    f32x4 s0 = vzero, s1 = vzero;
    __builtin_amdgcn_s_setprio(1);
#pragma unroll
    for (int kc = 0; kc < 16; kc++) {
      const int g = ((kc * 4 + lhi) ^ r7) << 3;
      bf8 bk0 = *(const bf8*)(k0row + g);
      bf8 bk1 = *(const bf8*)(k1row + g);
      s0 = __builtin_amdgcn_mfma_f32_16x16x32_bf16(qf[kc], bk0, s0, 0, 0, 0);
      s1 = __builtin_amdgcn_mfma_f32_16x16x32_bf16(qf[kc], bk1, s1, 0, 0, 0);
    }
    __builtin_amdgcn_s_setprio(0);
    {
      const int n = srt * 16 + lhi * 4;
#pragma unroll
      for (int r = 0; r < 4; r++) {
        Ss[n + r][sct0 * 16 + llo] = s0[r];
        Ss[n + r][sct0 * 16 + 16 + llo] = s1[r];
      }
    }
    __syncthreads();  // B2: S visible, all Ks reads done

    // prefetch next K tile (DMA; flies under softmax + PV, drained at next B1)
    if (it + 1 < NT)
      stage_tile(Kt + ((size_t)b * NN + m0 + KB) * CC, &Ks[0][0], wid, lane);

    // V fragments -> registers (latency hidden under softmax)
    bf8 av[2][4];
#pragma unroll
    for (int ks = 0; ks < 2; ks++)
#pragma unroll
      for (int rt = 0; rt < 4; rt++)
        av[ks][rt] = *(const bf8*)(vbase + (size_t)rt * 16 * NN + m0 + ks * 32);

    // online softmax: 8 threads per row; P packed to one swizzled b128 write
    {
      const int row = tid >> 3, j = tid & 7;
      const int rw7 = row & 7;
      float sv[8];
      *(float4*)&sv[0] = *(const float4*)&Ss[row][j * 8];
      *(float4*)&sv[4] = *(const float4*)&Ss[row][j * 8 + 4];
      float mx = fmaxf(fmaxf(fmaxf(sv[0], sv[1]), fmaxf(sv[2], sv[3])),
                       fmaxf(fmaxf(sv[4], sv[5]), fmaxf(sv[6], sv[7])));
      mx = fmaxf(mx, __shfl_xor(mx, 1, 8));
      mx = fmaxf(mx, __shfl_xor(mx, 2, 8));
      mx = fmaxf(mx, __shfl_xor(mx, 4, 8));
      const float mo = mst[row];
      const float nm = fmaxf(mo, mx);
      const float rs = __expf(mo - nm);
      float p[8], psum = 0.f;
#pragma unroll
      for (int k2 = 0; k2 < 8; k2++) {
        p[k2] = __expf(sv[k2] - nm);
        psum += p[k2];
      }
      bf8 pk;
#pragma unroll
      for (int k2 = 0; k2 < 8; k2++) pk[k2] = (short)f2bf(p[k2]);
      *(bf8*)(&Ps[row][0] + ((j ^ rw7) << 3)) = pk;
      psum += __shfl_xor(psum, 1, 8);
      psum += __shfl_xor(psum, 2, 8);
      psum += __shfl_xor(psum, 4, 8);
      if (j == 0) { lst[row] = lst[row] * rs + psum; mst[row] = nm; rsc[row] = rs; }
    }
    __syncthreads();  // B3: P + rsc ready

    // rescale (cols = n) then PV: acc[c][n] += V[c][m]·P[n][m]
    float rsn[4];
#pragma unroll
    for (int nt = 0; nt < 4; nt++) rsn[nt] = rsc[nt * 16 + llo];
#pragma unroll
    for (int rt = 0; rt < 4; rt++)
#pragma unroll
      for (int nt = 0; nt < 4; nt++) acc[rt][nt] *= rsn[nt];

    __builtin_amdgcn_s_setprio(1);
#pragma unroll
    for (int ks = 0; ks < 2; ks++) {
      bf8 bp[4];
#pragma unroll
      for (int nt = 0; nt < 4; nt++)
        bp[nt] = *(const bf8*)(&Ps[nt * 16 + llo][0] + ((((ks << 2) + lhi) ^ r7) << 3));
#pragma unroll
      for (int rt = 0; rt < 4; rt++)
#pragma unroll
        for (int nt = 0; nt < 4; nt++)
          acc[rt][nt] = __builtin_amdgcn_mfma_f32_16x16x32_bf16(av[ks][rt], bp[nt], acc[rt][nt], 0, 0, 0);
    }
    __builtin_amdgcn_s_setprio(0);
  }

  float invl[4];
#pragma unroll
  for (int nt = 0; nt < 4; nt++) invl[nt] = 1.0f / lst[nt * 16 + llo];

  // O[n][c] bf16 -> Os (swizzled granule layout)
  uint16_t(*Old)[CC] = Os;
#pragma unroll
  for (int rt = 0; rt < 4; rt++)
#pragma unroll
    for (int nt = 0; nt < 4; nt++) {
      ushort4 o4;
      o4.x = f2bf(acc[rt][nt][0] * invl[nt]);
      o4.y = f2bf(acc[rt][nt][1] * invl[nt]);
      o4.z = f2bf(acc[rt][nt][2] * invl[nt]);
      o4.w = f2bf(acc[rt][nt][3] * invl[nt]);
      const int gch = wid * 8 + rt * 2 + (lhi >> 1);
      *(ushort4*)(&Old[nt * 16 + llo][0] + ((gch ^ r7) << 3) + ((lhi & 1) << 2)) = o4;
    }

  // FFN: hidden in 4 d-quarters through Hs (overlay on Ks, swizzled)
  uint16_t(*Hs)[CC] = Ks;
  f32x4 facc[4][4];
#pragma unroll
  for (int i = 0; i < 4; i++)
#pragma unroll
    for (int j = 0; j < 4; j++) facc[i][j] = vzero;
  const float g = gma[0];
  const uint16_t* orow[4];
  const uint16_t* hrow[4];
#pragma unroll
  for (int nt = 0; nt < 4; nt++) {
    orow[nt] = &Old[nt * 16 + llo][0];
    hrow[nt] = &Hs[nt * 16 + llo][0];
  }

  for (int qtr = 0; qtr < 4; qtr++) {
    const int dq0 = qtr * 512;
    f32x4 hacc[4][4];
#pragma unroll
    for (int i = 0; i < 4; i++)
#pragma unroll
      for (int j = 0; j < 4; j++) hacc[i][j] = vzero;
    __syncthreads();  // prev quarter's Hs reads done; O-writes visible (qtr 0)
    __builtin_amdgcn_s_setprio(1);
#pragma unroll 2
    for (int kc8 = 0; kc8 < 64; kc8 += 4) {
      bf8 bo[4], aw[4];
      const int gof = ((kc8 + lhi) ^ r7) << 3;
#pragma unroll
      for (int nt = 0; nt < 4; nt++) bo[nt] = *(const bf8*)(orow[nt] + gof);
#pragma unroll
      for (int dt = 0; dt < 4; dt++) {
        const int d = dq0 + wid * 64 + dt * 16 + llo;
        aw[dt] = *(const bf8*)(W1b + (size_t)d * CC + (kc8 + lhi) * 8);
      }
#pragma unroll
      for (int dt = 0; dt < 4; dt++)
#pragma unroll
        for (int nt = 0; nt < 4; nt++)
          hacc[dt][nt] = __builtin_amdgcn_mfma_f32_16x16x32_bf16(aw[dt], bo[nt], hacc[dt][nt], 0, 0, 0);
    }
    __builtin_amdgcn_s_setprio(0);
#pragma unroll
    for (int dt = 0; dt < 4; dt++) {
      const int dg = dq0 + wid * 64 + dt * 16 + lhi * 4;
      const float4 b1v = *(const float4*)(b1 + dg);
#pragma unroll
      for (int nt = 0; nt < 4; nt++) {
        ushort4 h4;
        h4.x = f2bf(fmaxf(hacc[dt][nt][0] + b1v.x, 0.f));
        h4.y = f2bf(fmaxf(hacc[dt][nt][1] + b1v.y, 0.f));
        h4.z = f2bf(fmaxf(hacc[dt][nt][2] + b1v.z, 0.f));
        h4.w = f2bf(fmaxf(hacc[dt][nt][3] + b1v.w, 0.f));
        const int gch = wid * 8 + dt * 2 + (lhi >> 1);
        *(ushort4*)(&Hs[nt * 16 + llo][0] + ((gch ^ r7) << 3) + ((lhi & 1) << 2)) = h4;
      }
    }
    __syncthreads();  // hidden quarter ready
    __builtin_amdgcn_s_setprio(1);
#pragma unroll 2
    for (int kd8 = 0; kd8 < 64; kd8 += 4) {
      bf8 ah[4], bw[4];
      const int gof = ((kd8 + lhi) ^ r7) << 3;
#pragma unroll
      for (int nt = 0; nt < 4; nt++) ah[nt] = *(const bf8*)(hrow[nt] + gof);
#pragma unroll
      for (int ct = 0; ct < 4; ct++) {
        const int c = wid * 64 + ct * 16 + llo;
        bw[ct] = *(const bf8*)(W2b + (size_t)c * D4 + dq0 + (kd8 + lhi) * 8);
      }
#pragma unroll
      for (int nt = 0; nt < 4; nt++)
#pragma unroll
        for (int ct = 0; ct < 4; ct++)
          facc[nt][ct] = __builtin_amdgcn_mfma_f32_16x16x32_bf16(ah[nt], bw[ct], facc[nt][ct], 0, 0, 0);
    }
    __builtin_amdgcn_s_setprio(0);
  }

  // epilogue: out[b,c,n] = (facc + b2[c])*gamma + query  (float4 along n)
#pragma unroll
  for (int nt = 0; nt < 4; nt++) {
    const int n = n0 + nt * 16 + lhi * 4;
#pragma unroll
    for (int ct = 0; ct < 4; ct++) {
      const int c = wid * 64 + ct * 16 + llo;
      const float b2c = b2[c];
      const size_t off = ((size_t)b * CC + c) * NN + n;
      const float4 q4 = *(const float4*)(qry + off);
      float4 o4;
      o4.x = (facc[nt][ct][0] + b2c) * g + q4.x;
      o4.y = (facc[nt][ct][1] + b2c) * g + q4.y;
      o4.z = (facc[nt][ct][2] + b2c) * g + q4.z;
      o4.w = (facc[nt][ct][3] + b2c) * g + q4.w;
      *(float4*)(out + off) = o4;
    }
  }
}

extern "C" void kernel_launch(void* const* d_in, const int* in_sizes, int n_in,
                              void* d_out, int out_size, void* d_ws, size_t ws_size,
                              hipStream_t stream) {
  const float* q = (const float*)d_in[0];
  const float* k = (const float*)d_in[1];
  const float* v = (const float*)d_in[2];
  const float* w1 = (const float*)d_in[3];
  const float* b1 = (const float*)d_in[4];
  const float* w2 = (const float*)d_in[5];
  const float* b2 = (const float*)d_in[6];
  const float* gm = (const float*)d_in[7];
  float* out = (float*)d_out;

  uint16_t* Qt = (uint16_t*)d_ws;                    // [B][N][C] bf16 (pre-scaled)
  uint16_t* Kt = Qt + (size_t)BB * NN * CC;          // [B][N][C] bf16
  uint16_t* Vc = Kt + (size_t)BB * NN * CC;          // [B][C][N] bf16
  uint16_t* W1b = Vc + (size_t)BB * NN * CC;         // [2048][512] bf16
  uint16_t* W2b = W1b + (size_t)D4 * CC;             // [512][2048] bf16

  dim3 tgrid(NN / 32, CC / 32, BB);
  transpose_cast_k<<<tgrid, 256, 0, stream>>>(q, Qt, 0.044194173824159216f);
  transpose_cast_k<<<tgrid, 256, 0, stream>>>(k, Kt, 1.0f);
  cast_k<<<(BB * CC * NN / 4 + 255) / 256, 256, 0, stream>>>(v, Vc, BB * CC * NN);
  cast_k<<<(D4 * CC / 4 + 255) / 256, 256, 0, stream>>>(w1, W1b, D4 * CC);
  cast_k<<<(CC * D4 / 4 + 255) / 256, 256, 0, stream>>>(w2, W2b, CC * D4);
  attn_ffn_k<<<dim3(NN / QB, BB), 512, 0, stream>>>(Qt, Kt, Vc, W1b, W2b, b1, b2, gm, q, out);
}